// Round 6
// baseline (149.094 us; speedup 1.0000x reference)
//
#include <hip/hip_runtime.h>
#include <cstddef>

#define B_    4
#define CIN_  256
#define COUT_ 256
#define H_    64
#define W_    64
#define KK_   9
#define G_    4
#define NSL   36          // 4 groups * 9 taps, K=64 each
#define PW    80          // padded row width  (pad 8 each side)
#define PH    80          // padded rows       (pad 8 each side)
#define PADO  8           // pad offset

typedef short bf16x8 __attribute__((ext_vector_type(8)));
typedef float f32x4  __attribute__((ext_vector_type(4)));
typedef __attribute__((address_space(1))) const unsigned int* gptr_t;
typedef __attribute__((address_space(3))) unsigned int*       lptr_t;

__device__ __forceinline__ unsigned short f2bf(float v) {
    unsigned int u = __float_as_uint(v);
    u += 0x7fffu + ((u >> 16) & 1u);
    return (unsigned short)(u >> 16);
}
__device__ __forceinline__ float f_lo(unsigned int u) { return __uint_as_float(u << 16); }
__device__ __forceinline__ float f_hi(unsigned int u) { return __uint_as_float(u & 0xffff0000u); }

// Merged prep:
//   blocks [0,512):    xTp interior rows (x-borders zeroed inline)
//   blocks [512,576):  xTp border rows zero-fill
//   blocks [576,2880): wb weight repack (36 tiles, pos-swizzled)
__global__ __launch_bounds__(256) void prep_kernel(const float* __restrict__ x,
                                                   unsigned short* __restrict__ xTp,
                                                   const float* __restrict__ w,
                                                   unsigned short* __restrict__ wb) {
    const int tid = threadIdx.x;
    if (blockIdx.x < 512) {
        __shared__ unsigned short s[128][66];
        const int bh    = blockIdx.x >> 1;
        const int chalf = blockIdx.x & 1;
        const int b     = bh >> 6, h = bh & 63;
        const size_t src_base = ((size_t)b * CIN_ + chalf * 128) * (H_ * W_) + h * W_;
        #pragma unroll 4
        for (int k = 0; k < 32; ++k) {
            int i = k * 256 + tid;
            int c = i >> 6, ww = i & 63;
            s[c][ww] = f2bf(x[src_base + (size_t)c * (H_ * W_) + ww]);
        }
        __syncthreads();
        const size_t dst_row = ((size_t)b * PH + (h + PADO)) * PW;
        #pragma unroll 4
        for (int k = 0; k < 20; ++k) {              // 80 w' x 64 ch-pairs
            int j  = k * 256 + tid;
            int c2 = (j & 63) * 2, wp = j >> 6;     // wp in [0,80)
            unsigned int v = 0;
            if (wp >= PADO && wp < PADO + W_) {
                int ww = wp - PADO;
                v = (unsigned int)s[c2][ww] | ((unsigned int)s[c2 + 1][ww] << 16);
            }
            *(unsigned int*)(xTp + (dst_row + wp) * 256 + chalf * 128 + c2) = v;
        }
    } else if (blockIdx.x < 576) {
        const int bidx = blockIdx.x - 512;          // [0,64)
        const int b = bidx >> 4, rr = bidx & 15;
        const int yp = (rr < PADO) ? rr : (PH - 16 + rr);   // 0..7 or 72..79
        unsigned short* dst = xTp + ((size_t)b * PH + yp) * PW * 256;
        #pragma unroll
        for (int k = 0; k < 10; ++k) {              // 80*256 shorts = 2560 x 16B
            *(uint4*)(dst + (size_t)(k * 256 + tid) * 8) = make_uint4(0, 0, 0, 0);
        }
    } else {
        int idx = (blockIdx.x - 576) * 256 + tid;   // 36*16384 exactly
        int e   = idx & 7;
        int pos = (idx >> 3) & 7;
        int o   = (idx >> 6) & 255;
        int t   = idx >> 14;                        // g*9 + kk
        int g   = t / 9, kk = t - g * 9;
        int j   = pos ^ (o & 7);
        int c   = g * 64 + j * 8 + e;
        wb[idx] = f2bf(w[(o * CIN_ + c) * KK_ + kk]);
    }
}

// Main kernel: 256 blocks x 512 threads (8 waves, 1/CU). Wave = 128 outs x
// 16 px. REGISTER-DIRECT S-path: lane (l15=px, kq) gathers corner chunks at
// channel offsets {kq*8, kq*8+32} -> bilinear lands exactly in the lane's
// MFMA B-fragments (kh=0: chunk kq; kh=1: chunk kq+4). No S LDS, no ds_write,
// no lgkm at barriers. W: 3-buffer LDS, counted vmcnt, pure s_barrier.
__global__ __launch_bounds__(512, 2) void dcn_kernel(
    const unsigned short* __restrict__ xTp, const float* __restrict__ y,
    const float* __restrict__ w_off, const unsigned short* __restrict__ wb,
    float* __restrict__ out)
{
    __shared__ unsigned short s_W[3][COUT_ * 64];   // 3 x 32 KB

    const int tid = threadIdx.x;
    const int bid = blockIdx.x;                 // 256 blocks = 1/CU
    const int xcd = bid & 7;
    const int b   = xcd >> 1;
    const int h   = (xcd & 1) * 32 + (bid >> 3);

    const int lane = tid & 63, wave = tid >> 6;
    const int oh  = wave >> 2;        // out-half: outs [oh*128, +128)
    const int wq  = wave & 3;         // px-quarter: px [wq*16, +16)
    const int l15 = lane & 15, kq = lane >> 4, swz = l15 & 7;
    const int px  = wq * 16 + l15;

    const float yv0 = y[((b * 2 + 0) * H_ + h) * W_ + px];
    const float yv1 = y[((b * 2 + 1) * H_ + h) * W_ + px];
    const float spf = (float)(px - 1 + PADO);
    const float hpf = (float)(h  - 1 + PADO);

    f32x4 acc[8];   // 8 m-tiles of 16 outs x (16 px)
    #pragma unroll
    for (int i = 0; i < 8; ++i) acc[i] = (f32x4){0.f, 0.f, 0.f, 0.f};

    // gather base: batch + this lane's k-chunk (kq*8 channels)
    const unsigned short* xb = xTp + (size_t)b * (PH * PW * 256) + kq * 8;

    // A-fragment LDS pointers (per buffer, per kh). Row = oh*128 + l15;
    // pos = ((kh*4+kq) ^ swz): cancels wb's pre-swizzle -> ch (kh*4+kq)*8.
    const int a_off0 = (oh * 128 + l15) * 64 + ((kq       ^ swz) * 8);
    const int a_off1 = (oh * 128 + l15) * 64 + (((4 + kq) ^ swz) * 8);
    const unsigned short* wA0 = &s_W[0][a_off0];
    const unsigned short* wA1 = &s_W[0][a_off1];
    const unsigned short* wB0 = &s_W[1][a_off0];
    const unsigned short* wB1 = &s_W[1][a_off1];
    const unsigned short* wC0 = &s_W[2][a_off0];
    const unsigned short* wC1 = &s_W[2][a_off1];

    // in-flight sample state (one step ahead)
    float w00, w01, w10, w11;
    uint4 cA0, cA1, cB0, cB1, cC0, cC1, cD0, cD1;
    bf16x8 bfr0, bfr1;

#define ISSUE_G(t) do {                                                        \
    const int t_ = (t);                                                        \
    const int g_ = t_ / 9, kk_ = t_ - g_ * 9;                                  \
    const float4 co = *(const float4*)(w_off + t_ * 4);                        \
    const float dy = fmaf(yv0, co.x, yv1 * co.y);                              \
    const float dx = fmaf(yv0, co.z, yv1 * co.w);                              \
    const float yc = hpf + (float)(kk_ / 3) + dy;                              \
    const float xc = spf + (float)(kk_ % 3) + dx;                              \
    const float yf = floorf(yc), xf = floorf(xc);                              \
    const float wy = yc - yf, wx = xc - xf;                                    \
    const int   yi = (int)yf, xi = (int)xf;     /* padded coords, >= 0 */      \
    const float omy = 1.f - wy, omx = 1.f - wx;                                \
    w00 = omy * omx; w01 = omy * wx; w10 = wy * omx; w11 = wy * wx;            \
    const unsigned short* p0 = xb + (yi * PW + xi) * 256 + g_ * 64;            \
    const unsigned short* p1 = p0 + PW * 256;                                  \
    cA0 = *(const uint4*)(p0);        cA1 = *(const uint4*)(p0 + 32);          \
    cB0 = *(const uint4*)(p0 + 256);  cB1 = *(const uint4*)(p0 + 288);         \
    cC0 = *(const uint4*)(p1);        cC1 = *(const uint4*)(p1 + 32);          \
    cD0 = *(const uint4*)(p1 + 256);  cD1 = *(const uint4*)(p1 + 288);         \
} while (0)

#define STAGE_W(t, buf) do {                                                   \
    const unsigned short* src = wb + (size_t)(t) * 16384;                      \
    _Pragma("unroll")                                                          \
    for (int j = 0; j < 4; ++j) {                                              \
        const int off = (j * 512 + tid) * 8;                                   \
        __builtin_amdgcn_global_load_lds((gptr_t)(src + off),                  \
                                         (lptr_t)(s_W[buf] + off), 16, 0, 0); \
    }                                                                          \
} while (0)

#define BILIN1(Aq, Bq, Cq, Dq, dst) do {                                       \
    const unsigned int av[4] = {Aq.x, Aq.y, Aq.z, Aq.w};                       \
    const unsigned int bv[4] = {Bq.x, Bq.y, Bq.z, Bq.w};                       \
    const unsigned int cv[4] = {Cq.x, Cq.y, Cq.z, Cq.w};                       \
    const unsigned int dv[4] = {Dq.x, Dq.y, Dq.z, Dq.w};                       \
    unsigned int o[4];                                                         \
    _Pragma("unroll")                                                          \
    for (int q = 0; q < 4; ++q) {                                              \
        float rl = w00 * f_lo(av[q]);                                          \
        rl = fmaf(w01, f_lo(bv[q]), rl);                                       \
        rl = fmaf(w10, f_lo(cv[q]), rl);                                       \
        rl = fmaf(w11, f_lo(dv[q]), rl);                                       \
        float rh = w00 * f_hi(av[q]);                                          \
        rh = fmaf(w01, f_hi(bv[q]), rh);                                       \
        rh = fmaf(w10, f_hi(cv[q]), rh);                                       \
        rh = fmaf(w11, f_hi(dv[q]), rh);                                       \
        o[q] = __builtin_amdgcn_perm(__float_as_uint(rh),                      \
                                     __float_as_uint(rl), 0x07060302u);        \
    }                                                                          \
    uint4 pk = make_uint4(o[0], o[1], o[2], o[3]);                             \
    dst = *(bf16x8*)&pk;                                                       \
} while (0)

#define MFMA_HALF(wp, bfr) do {                                                \
    bf16x8 a0 = *(const bf16x8*)((wp));                                        \
    bf16x8 a1 = *(const bf16x8*)((wp) + 1024);                                 \
    bf16x8 a2 = *(const bf16x8*)((wp) + 2048);                                 \
    bf16x8 a3 = *(const bf16x8*)((wp) + 3072);                                 \
    bf16x8 a4 = *(const bf16x8*)((wp) + 4096);                                 \
    bf16x8 a5 = *(const bf16x8*)((wp) + 5120);                                 \
    bf16x8 a6 = *(const bf16x8*)((wp) + 6144);                                 \
    bf16x8 a7 = *(const bf16x8*)((wp) + 7168);                                 \
    __builtin_amdgcn_s_setprio(1);                                             \
    acc[0] = __builtin_amdgcn_mfma_f32_16x16x32_bf16(a0, bfr, acc[0], 0,0,0);  \
    acc[1] = __builtin_amdgcn_mfma_f32_16x16x32_bf16(a1, bfr, acc[1], 0,0,0);  \
    acc[2] = __builtin_amdgcn_mfma_f32_16x16x32_bf16(a2, bfr, acc[2], 0,0,0);  \
    acc[3] = __builtin_amdgcn_mfma_f32_16x16x32_bf16(a3, bfr, acc[3], 0,0,0);  \
    acc[4] = __builtin_amdgcn_mfma_f32_16x16x32_bf16(a4, bfr, acc[4], 0,0,0);  \
    acc[5] = __builtin_amdgcn_mfma_f32_16x16x32_bf16(a5, bfr, acc[5], 0,0,0);  \
    acc[6] = __builtin_amdgcn_mfma_f32_16x16x32_bf16(a6, bfr, acc[6], 0,0,0);  \
    acc[7] = __builtin_amdgcn_mfma_f32_16x16x32_bf16(a7, bfr, acc[7], 0,0,0);  \
    __builtin_amdgcn_s_setprio(0);                                             \
} while (0)

// Step s. Entering (steady): outstanding vmem = G(s)[8] (oldest), DMA(s+1)[4].
// vmcnt(4) retires G(s) -> BILIN builds B-frags in regs. Issue G(s+1)[8],
// DMA(s+2)[4] -> 16 outstanding. vmcnt(12) retires DMA(s+1) (oldest) before
// the barrier; G(s+1)+DMA(s+2) cross in flight. No lgkm wait needed: ds_reads
// are drained by MFMA data-deps, and there are no ds_writes.
#define STEP(s_, WP0, WP1, WPRE, DO_STG, VEND) do {                            \
    asm volatile("s_waitcnt vmcnt(4)" ::: "memory");                           \
    __builtin_amdgcn_sched_barrier(0);                                         \
    BILIN1(cA0, cB0, cC0, cD0, bfr0);                                          \
    BILIN1(cA1, cB1, cC1, cD1, bfr1);                                          \
    __builtin_amdgcn_sched_barrier(0);                                         \
    ISSUE_G((s_) + 1);                                                         \
    __builtin_amdgcn_sched_barrier(0);                                         \
    if (DO_STG) STAGE_W((s_) + 2, WPRE);                                       \
    __builtin_amdgcn_sched_barrier(0);                                         \
    MFMA_HALF(WP0, bfr0);                                                      \
    MFMA_HALF(WP1, bfr1);                                                      \
    __builtin_amdgcn_sched_barrier(0);                                         \
    asm volatile("s_waitcnt vmcnt(" #VEND ")" ::: "memory");                   \
    __builtin_amdgcn_sched_barrier(0);                                         \
    __builtin_amdgcn_s_barrier();                                              \
    __builtin_amdgcn_sched_barrier(0);                                         \
} while (0)

    // ---- prologue: G(0), W(0), W(1); retire G(0)+W(0); W(1) stays in flight
    ISSUE_G(0);
    __builtin_amdgcn_sched_barrier(0);
    STAGE_W(0, 0);
    STAGE_W(1, 1);
    __builtin_amdgcn_sched_barrier(0);
    asm volatile("s_waitcnt vmcnt(4)" ::: "memory");   // leaves W(1)[4]
    __builtin_amdgcn_sched_barrier(0);
    __builtin_amdgcn_s_barrier();
    __builtin_amdgcn_sched_barrier(0);

    // ---- main loop: steps 0..32, buffer pattern period 3 ----
    for (int s0 = 0; s0 < 33; s0 += 3) {
        STEP(s0 + 0, wA0, wA1, 2, 1, 12);
        STEP(s0 + 1, wB0, wB1, 0, 1, 12);
        STEP(s0 + 2, wC0, wC1, 1, 1, 12);
    }
    STEP(33, wA0, wA1, 2, 1, 12);
    STEP(34, wB0, wB1, 0, 0, 8);       // no STAGE(36); retire DMA(35)

    // ---- step 35: final (no barrier, no prefetch) ----
    asm volatile("s_waitcnt vmcnt(0)" ::: "memory");
    __builtin_amdgcn_sched_barrier(0);
    BILIN1(cA0, cB0, cC0, cD0, bfr0);
    BILIN1(cA1, cB1, cC1, cD1, bfr1);
    MFMA_HALF(wC0, bfr0);
    MFMA_HALF(wC1, bfr1);

    // ---- epilogue: fused relu. C/D: col=l15=px, row=kq*4+rr ----
    #pragma unroll
    for (int mt = 0; mt < 8; ++mt) {
        const int obase = oh * 128 + mt * 16 + kq * 4;
        #pragma unroll
        for (int rr = 0; rr < 4; ++rr) {
            out[(((size_t)b * COUT_ + obase + rr) * H_ + h) * W_ + px] =
                fmaxf(acc[mt][rr], 0.f);
        }
    }
#undef ISSUE_G
#undef STAGE_W
#undef BILIN1
#undef MFMA_HALF
#undef STEP
}

extern "C" void kernel_launch(void* const* d_in, const int* in_sizes, int n_in,
                              void* d_out, int out_size, void* d_ws, size_t ws_size,
                              hipStream_t stream) {
    const float* x     = (const float*)d_in[0];
    const float* y     = (const float*)d_in[1];
    const float* w_off = (const float*)d_in[2];
    const float* w_def = (const float*)d_in[3];
    float* out = (float*)d_out;

    unsigned short* xTp = (unsigned short*)d_ws;            // 4*80*80*256*2B = 13.1 MB
    unsigned short* wb  = (unsigned short*)d_ws + (size_t)B_ * PH * PW * 256;  // 1.18 MB

    prep_kernel<<<2880, 256, 0, stream>>>(x, xTp, w_def, wb);
    dcn_kernel<<<256, 512, 0, stream>>>(xTp, y, w_off, wb, out);
}

// Round 7
// 121.058 us; speedup vs baseline: 1.2316x; 1.2316x over previous
//
#include <hip/hip_runtime.h>
#include <cstddef>

#define B_    4
#define CIN_  256
#define COUT_ 256
#define H_    64
#define W_    64
#define KK_   9
#define G_    4
#define NP    18          // 18 barrier-steps, each = 2 taps (K=128)
#define PW    80          // padded row width  (pad 8 each side)
#define PH    80          // padded rows       (pad 8 each side)
#define PADO  8           // pad offset

typedef short bf16x8 __attribute__((ext_vector_type(8)));
typedef float f32x4  __attribute__((ext_vector_type(4)));
typedef __attribute__((address_space(1))) const unsigned int* gptr_t;
typedef __attribute__((address_space(3))) unsigned int*       lptr_t;

__device__ __forceinline__ unsigned short f2bf(float v) {
    unsigned int u = __float_as_uint(v);
    u += 0x7fffu + ((u >> 16) & 1u);
    return (unsigned short)(u >> 16);
}
__device__ __forceinline__ float f_lo(unsigned int u) { return __uint_as_float(u << 16); }
__device__ __forceinline__ float f_hi(unsigned int u) { return __uint_as_float(u & 0xffff0000u); }

// Merged prep:
//   blocks [0,512):    xTp interior rows (x-borders zeroed inline)
//   blocks [512,576):  xTp border rows zero-fill
//   blocks [576,2880): wb weight repack (36 tiles, pos-swizzled)
__global__ __launch_bounds__(256) void prep_kernel(const float* __restrict__ x,
                                                   unsigned short* __restrict__ xTp,
                                                   const float* __restrict__ w,
                                                   unsigned short* __restrict__ wb) {
    const int tid = threadIdx.x;
    if (blockIdx.x < 512) {
        __shared__ unsigned short s[128][66];
        const int bh    = blockIdx.x >> 1;
        const int chalf = blockIdx.x & 1;
        const int b     = bh >> 6, h = bh & 63;
        const size_t src_base = ((size_t)b * CIN_ + chalf * 128) * (H_ * W_) + h * W_;
        #pragma unroll 4
        for (int k = 0; k < 32; ++k) {
            int i = k * 256 + tid;
            int c = i >> 6, ww = i & 63;
            s[c][ww] = f2bf(x[src_base + (size_t)c * (H_ * W_) + ww]);
        }
        __syncthreads();
        const size_t dst_row = ((size_t)b * PH + (h + PADO)) * PW;
        #pragma unroll 4
        for (int k = 0; k < 20; ++k) {              // 80 w' x 64 ch-pairs
            int j  = k * 256 + tid;
            int c2 = (j & 63) * 2, wp = j >> 6;     // wp in [0,80)
            unsigned int v = 0;
            if (wp >= PADO && wp < PADO + W_) {
                int ww = wp - PADO;
                v = (unsigned int)s[c2][ww] | ((unsigned int)s[c2 + 1][ww] << 16);
            }
            *(unsigned int*)(xTp + (dst_row + wp) * 256 + chalf * 128 + c2) = v;
        }
    } else if (blockIdx.x < 576) {
        const int bidx = blockIdx.x - 512;          // [0,64)
        const int b = bidx >> 4, rr = bidx & 15;
        const int yp = (rr < PADO) ? rr : (PH - 16 + rr);   // 0..7 or 72..79
        unsigned short* dst = xTp + ((size_t)b * PH + yp) * PW * 256;
        #pragma unroll
        for (int k = 0; k < 10; ++k) {              // 80*256 shorts = 2560 x 16B
            *(uint4*)(dst + (size_t)(k * 256 + tid) * 8) = make_uint4(0, 0, 0, 0);
        }
    } else {
        int idx = (blockIdx.x - 576) * 256 + tid;   // 36*16384 exactly
        int e   = idx & 7;
        int pos = (idx >> 3) & 7;
        int o   = (idx >> 6) & 255;
        int t   = idx >> 14;                        // g*9 + kk
        int g   = t / 9, kk = t - g * 9;
        int j   = pos ^ (o & 7);
        int c   = g * 64 + j * 8 + e;
        wb[idx] = f2bf(w[(o * CIN_ + c) * KK_ + kk]);
    }
}

// Main kernel: 256 blocks x 512 threads (8 waves, 1/CU), LDS 160 KB.
// Block = (b,h): 256 outs x 64 px. 18 barrier-steps, each = TAP PAIR (K=128):
// per-step fixed overhead (gather latency, barrier, phase turnaround) is paid
// 18x instead of 36x; the 2x MFMA cluster (~1200 cy) fully covers gather
// latency and the W DMA has the whole step (~3500 cy) to land -> end-of-step
// vmcnt(0) is free. Structure is round-2's proven S-path, K-doubled.
__global__ __launch_bounds__(512, 2) void dcn_kernel(
    const unsigned short* __restrict__ xTp, const float* __restrict__ y,
    const float* __restrict__ w_off, const unsigned short* __restrict__ wb,
    float* __restrict__ out)
{
    __shared__ unsigned short s_W[2][2][16384];   // [buf][tap-half][256o*64c] 128 KB
    __shared__ unsigned short s_S[2][2][4096];    // [buf][tap-half][64px*64c]  32 KB

    const int tid = threadIdx.x;
    const int bid = blockIdx.x;                 // 256 blocks = 1/CU
    const int xcd = bid & 7;
    const int b   = xcd >> 1;
    const int h   = (xcd & 1) * 32 + (bid >> 3);

    // sampling mapping: 8 threads per pixel, 8 channels (16B) each
    const int sp = tid >> 3;          // pixel 0..63
    const int c8 = tid & 7;           // 8-ch chunk 0..7

    const float yv0 = y[((b * 2 + 0) * H_ + h) * W_ + sp];
    const float yv1 = y[((b * 2 + 1) * H_ + h) * W_ + sp];
    const float spf = (float)(sp - 1 + PADO);       // x base (pre-padded)
    const float hpf = (float)(h  - 1 + PADO);       // y base (pre-padded)

    // mfma mapping: 8 waves, wave = 64 outs (oh) x 32 px (pg)
    const int lane = tid & 63, wave = tid >> 6;
    const int pg  = wave & 1, oh = wave >> 1;       // oh 0..3
    const int l15 = lane & 15, kq = lane >> 4, sw = l15 & 7;

    f32x4 acc[8];   // [nt][mt] : 2 px-subtiles x 4 out-subtiles
    #pragma unroll
    for (int i = 0; i < 8; ++i) acc[i] = (f32x4){0.f, 0.f, 0.f, 0.f};

    const unsigned short* xb = xTp + (size_t)b * (PH * PW * 256) + c8 * 8;

    // two tap slots in flight (all indices compile-time -- rule #20)
    float wgt[2][4];
    uint4 gA[2], gB[2], gC[2], gD[2];

#define ISSUE_ONE(t, P) do {                                                   \
    const int t_ = (t);                                                        \
    const int g_ = t_ / 9, kk_ = t_ - g_ * 9;                                  \
    const float4 co = *(const float4*)(w_off + t_ * 4);                        \
    const float dy = fmaf(yv0, co.x, yv1 * co.y);                              \
    const float dx = fmaf(yv0, co.z, yv1 * co.w);                              \
    const float yc = hpf + (float)(kk_ / 3) + dy;                              \
    const float xc = spf + (float)(kk_ % 3) + dx;                              \
    const float yf = floorf(yc), xf = floorf(xc);                              \
    const float wy = yc - yf, wx = xc - xf;                                    \
    const int   yi = (int)yf, xi = (int)xf;     /* padded coords, >= 0 */      \
    const float omy = 1.f - wy, omx = 1.f - wx;                                \
    wgt[P][0] = omy * omx; wgt[P][1] = omy * wx;                               \
    wgt[P][2] = wy * omx;  wgt[P][3] = wy * wx;                                \
    const unsigned short* p0 = xb + (yi * PW + xi) * 256 + g_ * 64;            \
    const unsigned short* p1 = p0 + PW * 256;                                  \
    gA[P] = *(const uint4*)(p0);        gB[P] = *(const uint4*)(p0 + 256);     \
    gC[P] = *(const uint4*)(p1);        gD[P] = *(const uint4*)(p1 + 256);     \
} while (0)

// stage one PAIR (2 consecutive wb tiles = 64 KB) into s_W[buf]
#define STAGE_W2(t, buf) do {                                                  \
    const unsigned short* src = wb + (size_t)(t) * 32768;                      \
    _Pragma("unroll")                                                          \
    for (int j = 0; j < 8; ++j) {                                              \
        const int off = (j * 512 + tid) * 8;                                   \
        __builtin_amdgcn_global_load_lds((gptr_t)(src + off),                  \
                                         (lptr_t)(&s_W[buf][0][0] + off),      \
                                         16, 0, 0);                            \
    }                                                                          \
} while (0)

#define WRITE_ONE(P, SB) do {                                                  \
    const unsigned int av[4] = {gA[P].x, gA[P].y, gA[P].z, gA[P].w};           \
    const unsigned int bv[4] = {gB[P].x, gB[P].y, gB[P].z, gB[P].w};           \
    const unsigned int cv[4] = {gC[P].x, gC[P].y, gC[P].z, gC[P].w};           \
    const unsigned int dv[4] = {gD[P].x, gD[P].y, gD[P].z, gD[P].w};           \
    unsigned int res[4];                                                       \
    _Pragma("unroll")                                                          \
    for (int q = 0; q < 4; ++q) {                                              \
        float rl = wgt[P][0] * f_lo(av[q]);                                    \
        rl = fmaf(wgt[P][1], f_lo(bv[q]), rl);                                 \
        rl = fmaf(wgt[P][2], f_lo(cv[q]), rl);                                 \
        rl = fmaf(wgt[P][3], f_lo(dv[q]), rl);                                 \
        float rh = wgt[P][0] * f_hi(av[q]);                                    \
        rh = fmaf(wgt[P][1], f_hi(bv[q]), rh);                                 \
        rh = fmaf(wgt[P][2], f_hi(cv[q]), rh);                                 \
        rh = fmaf(wgt[P][3], f_hi(dv[q]), rh);                                 \
        res[q] = __builtin_amdgcn_perm(__float_as_uint(rh),                    \
                                       __float_as_uint(rl), 0x07060302u);      \
    }                                                                          \
    *(uint4*)(&s_S[SB][P][0] + sp * 64 + ((c8 ^ (sp & 7)) * 8)) =              \
        make_uint4(res[0], res[1], res[2], res[3]);                            \
} while (0)

// one K=64 MFMA block: W buf WB, tap-half HF, S buf SB (r2-proven layout)
#define MFMA_TAP(WB, HF, SB) do {                                              \
    bf16x8 bf[2][2], af[2][4];                                                 \
    _Pragma("unroll")                                                          \
    for (int kh = 0; kh < 2; ++kh) {                                           \
        const int pos = ((kh * 4 + kq) ^ sw) * 8;                              \
        _Pragma("unroll")                                                      \
        for (int nt = 0; nt < 2; ++nt)                                         \
            bf[kh][nt] = *(const bf16x8*)(&s_S[SB][HF][0] +                    \
                              (pg * 32 + nt * 16 + l15) * 64 + pos);           \
        _Pragma("unroll")                                                      \
        for (int mt = 0; mt < 4; ++mt)                                         \
            af[kh][mt] = *(const bf16x8*)(&s_W[WB][HF][0] +                    \
                              (oh * 64 + mt * 16 + l15) * 64 + pos);           \
    }                                                                          \
    __builtin_amdgcn_s_setprio(1);                                             \
    _Pragma("unroll")                                                          \
    for (int kh = 0; kh < 2; ++kh)                                             \
        _Pragma("unroll")                                                      \
        for (int nt = 0; nt < 2; ++nt)                                         \
            _Pragma("unroll")                                                  \
            for (int mt = 0; mt < 4; ++mt)                                     \
                acc[nt * 4 + mt] = __builtin_amdgcn_mfma_f32_16x16x32_bf16(    \
                    af[kh][mt], bf[kh][nt], acc[nt * 4 + mt], 0, 0, 0);        \
    __builtin_amdgcn_s_setprio(0);                                             \
} while (0)

// Pair-step s (P = s&1). Issue gathers(pair s+1) + DMA(pair s+1 -> buf P^1),
// MFMA both tap-halves of pair s, bilinear+write S(pair s+1) into buf P^1
// (auto-wait vmcnt(8) retires the gathers under the MFMA cluster), then
// drain (free: DMA had the whole step) and barrier.
#define STEP(s_, P, DO_PF) do {                                                \
    if (DO_PF) { ISSUE_ONE(2 * (s_) + 2, 0); ISSUE_ONE(2 * (s_) + 3, 1); }     \
    __builtin_amdgcn_sched_barrier(0);                                         \
    if (DO_PF) STAGE_W2((s_) + 1, P ^ 1);                                      \
    __builtin_amdgcn_sched_barrier(0);                                         \
    MFMA_TAP(P, 0, P);                                                         \
    MFMA_TAP(P, 1, P);                                                         \
    __builtin_amdgcn_sched_barrier(0);                                         \
    if (DO_PF) { WRITE_ONE(0, P ^ 1); WRITE_ONE(1, P ^ 1); }                   \
    __builtin_amdgcn_sched_barrier(0);                                         \
    asm volatile("s_waitcnt vmcnt(0) lgkmcnt(0)" ::: "memory");                \
    __builtin_amdgcn_sched_barrier(0);                                         \
    __builtin_amdgcn_s_barrier();                                              \
    __builtin_amdgcn_sched_barrier(0);                                         \
} while (0)

    // ---- prologue: gather+stage pair 0, write S[0], drain, barrier ----
    ISSUE_ONE(0, 0);
    ISSUE_ONE(1, 1);
    __builtin_amdgcn_sched_barrier(0);
    STAGE_W2(0, 0);
    __builtin_amdgcn_sched_barrier(0);
    WRITE_ONE(0, 0);                 // auto vmcnt(8): retires gathers
    WRITE_ONE(1, 0);
    __builtin_amdgcn_sched_barrier(0);
    asm volatile("s_waitcnt vmcnt(0) lgkmcnt(0)" ::: "memory");
    __builtin_amdgcn_sched_barrier(0);
    __builtin_amdgcn_s_barrier();
    __builtin_amdgcn_sched_barrier(0);

    // ---- main loop: pairs 0..15 (static buf indices), then 16, then 17 ----
    for (int sb = 0; sb < 16; sb += 2) {
        STEP(sb + 0, 0, 1);
        STEP(sb + 1, 1, 1);
    }
    STEP(16, 0, 1);                   // prefetches pair 17 -> buf1 / S[1]
    MFMA_TAP(1, 0, 1);                // pair 17, no barrier before epilogue
    MFMA_TAP(1, 1, 1);

    // ---- epilogue: fused relu, direct final store. C/D: col->px, row->o ----
    #pragma unroll
    for (int nt = 0; nt < 2; ++nt) {
        const int px = pg * 32 + nt * 16 + l15;
        #pragma unroll
        for (int mt = 0; mt < 4; ++mt) {
            const int obase = oh * 64 + mt * 16 + kq * 4;
            #pragma unroll
            for (int rr = 0; rr < 4; ++rr) {
                out[(((size_t)b * COUT_ + obase + rr) * H_ + h) * W_ + px] =
                    fmaxf(acc[nt * 4 + mt][rr], 0.f);
            }
        }
    }
#undef ISSUE_ONE
#undef STAGE_W2
#undef WRITE_ONE
#undef MFMA_TAP
#undef STEP
}

extern "C" void kernel_launch(void* const* d_in, const int* in_sizes, int n_in,
                              void* d_out, int out_size, void* d_ws, size_t ws_size,
                              hipStream_t stream) {
    const float* x     = (const float*)d_in[0];
    const float* y     = (const float*)d_in[1];
    const float* w_off = (const float*)d_in[2];
    const float* w_def = (const float*)d_in[3];
    float* out = (float*)d_out;

    unsigned short* xTp = (unsigned short*)d_ws;            // 4*80*80*256*2B = 13.1 MB
    unsigned short* wb  = (unsigned short*)d_ws + (size_t)B_ * PH * PW * 256;  // 1.18 MB

    prep_kernel<<<2880, 256, 0, stream>>>(x, xTp, w_def, wb);
    dcn_kernel<<<256, 512, 0, stream>>>(xTp, y, w_off, wb, out);
}

// Round 8
// 120.460 us; speedup vs baseline: 1.2377x; 1.0050x over previous
//
#include <hip/hip_runtime.h>
#include <cstddef>

#define B_    4
#define CIN_  256
#define COUT_ 256
#define H_    64
#define W_    64
#define KK_   9
#define G_    4
#define PW    80          // padded row width  (pad 8 each side)
#define PH    80          // padded rows
#define PADO  8           // pad offset

typedef short bf16x8 __attribute__((ext_vector_type(8)));
typedef float f32x4  __attribute__((ext_vector_type(4)));
typedef __attribute__((address_space(1))) const unsigned int* gptr_t;
typedef __attribute__((address_space(3))) unsigned int*       lptr_t;

__device__ __forceinline__ unsigned short f2bf(float v) {
    unsigned int u = __float_as_uint(v);
    u += 0x7fffu + ((u >> 16) & 1u);
    return (unsigned short)(u >> 16);
}
__device__ __forceinline__ float f_lo(unsigned int u) { return __uint_as_float(u << 16); }
__device__ __forceinline__ float f_hi(unsigned int u) { return __uint_as_float(u & 0xffff0000u); }

// Merged prep (unchanged from r7):
//   blocks [0,512):    xTp interior rows (x-borders zeroed inline)
//   blocks [512,576):  xTp border rows zero-fill
//   blocks [576,2880): wb weight repack (36 tiles, pos-swizzled)
__global__ __launch_bounds__(256) void prep_kernel(const float* __restrict__ x,
                                                   unsigned short* __restrict__ xTp,
                                                   const float* __restrict__ w,
                                                   unsigned short* __restrict__ wb) {
    const int tid = threadIdx.x;
    if (blockIdx.x < 512) {
        __shared__ unsigned short s[128][66];
        const int bh    = blockIdx.x >> 1;
        const int chalf = blockIdx.x & 1;
        const int b     = bh >> 6, h = bh & 63;
        const size_t src_base = ((size_t)b * CIN_ + chalf * 128) * (H_ * W_) + h * W_;
        #pragma unroll 4
        for (int k = 0; k < 32; ++k) {
            int i = k * 256 + tid;
            int c = i >> 6, ww = i & 63;
            s[c][ww] = f2bf(x[src_base + (size_t)c * (H_ * W_) + ww]);
        }
        __syncthreads();
        const size_t dst_row = ((size_t)b * PH + (h + PADO)) * PW;
        #pragma unroll 4
        for (int k = 0; k < 20; ++k) {              // 80 w' x 64 ch-pairs
            int j  = k * 256 + tid;
            int c2 = (j & 63) * 2, wp = j >> 6;     // wp in [0,80)
            unsigned int v = 0;
            if (wp >= PADO && wp < PADO + W_) {
                int ww = wp - PADO;
                v = (unsigned int)s[c2][ww] | ((unsigned int)s[c2 + 1][ww] << 16);
            }
            *(unsigned int*)(xTp + (dst_row + wp) * 256 + chalf * 128 + c2) = v;
        }
    } else if (blockIdx.x < 576) {
        const int bidx = blockIdx.x - 512;          // [0,64)
        const int b = bidx >> 4, rr = bidx & 15;
        const int yp = (rr < PADO) ? rr : (PH - 16 + rr);   // 0..7 or 72..79
        unsigned short* dst = xTp + ((size_t)b * PH + yp) * PW * 256;
        #pragma unroll
        for (int k = 0; k < 10; ++k) {
            *(uint4*)(dst + (size_t)(k * 256 + tid) * 8) = make_uint4(0, 0, 0, 0);
        }
    } else {
        int idx = (blockIdx.x - 576) * 256 + tid;   // 36*16384 exactly
        int e   = idx & 7;
        int pos = (idx >> 3) & 7;
        int o   = (idx >> 6) & 255;
        int t   = idx >> 14;                        // g*9 + kk
        int g   = t / 9, kk = t - g * 9;
        int j   = pos ^ (o & 7);
        int c   = g * 64 + j * 8 + e;
        wb[idx] = f2bf(w[(o * CIN_ + c) * KK_ + kk]);
    }
}

// Main kernel: 256 blocks x 512 threads, 1/CU, LDS 112 KB.
// PRODUCER/CONSUMER WAVE SPECIALIZATION:
//   waves 0-3 (consumers, 1/SIMD): 64 outs x 64 px each; 16 ds_read_b128 +
//     32 MFMA per tap. af has ZERO duplication (each wave unique outs).
//   waves 4-7 (producers, 1/SIMD): all sampling (4 thr/px x 2 chunks),
//     bilinear, S-writes, W-DMA. 2-set gather pipeline (full-tap latency
//     cover); W 3-buffer, counted vmcnt, never drained in the loop.
// Between barriers, producer VALU/TA runs concurrently with consumer
// LDS/MFMA on every SIMD -- pipe overlap by construction, not scheduling.
__global__ __launch_bounds__(512, 2) void dcn_kernel(
    const unsigned short* __restrict__ xTp, const float* __restrict__ y,
    const float* __restrict__ w_off, const unsigned short* __restrict__ wb,
    float* __restrict__ out)
{
    __shared__ unsigned short s_W[3][16384];    // 3 x 32 KB  [o 0..255][ch-pos]
    __shared__ unsigned short s_S[2][4096];     // 2 x  8 KB  [px][ch-pos swz]

    const int tid = threadIdx.x;
    const int bid = blockIdx.x;                 // 256 blocks = 1/CU
    const int xcd = bid & 7;
    const int b   = xcd >> 1;
    const int h   = (xcd & 1) * 32 + (bid >> 3);
    const int lane = tid & 63, wave = tid >> 6;

#define BAR() do {                                                             \
    __builtin_amdgcn_sched_barrier(0);                                         \
    __builtin_amdgcn_s_barrier();                                              \
    __builtin_amdgcn_sched_barrier(0);                                         \
} while (0)

    if (wave >= 4) {
        // ================= PRODUCERS (waves 4-7) =================
        const int ptid = tid - 256;
        const int sp = ptid >> 2;           // pixel 0..63
        const int cq = (ptid & 3) * 2;      // first chunk of the pair

        const float yv0 = y[((b * 2 + 0) * H_ + h) * W_ + sp];
        const float yv1 = y[((b * 2 + 1) * H_ + h) * W_ + sp];
        const float spf = (float)(sp - 1 + PADO);
        const float hpf = (float)(h  - 1 + PADO);

        const unsigned short* xb = xTp + (size_t)b * (PH * PW * 256) + cq * 8;

        float wgt[2][4];
        uint4 gA[2][2], gB[2][2], gC[2][2], gD[2][2];   // [set][chunk]

#define ISSUE_G(t, P) do {                                                     \
    const int t_ = (t);                                                        \
    const int g_ = t_ / 9, kk_ = t_ - g_ * 9;                                  \
    const float4 co = *(const float4*)(w_off + t_ * 4);                        \
    const float dy = fmaf(yv0, co.x, yv1 * co.y);                              \
    const float dx = fmaf(yv0, co.z, yv1 * co.w);                              \
    const float yc = hpf + (float)(kk_ / 3) + dy;                              \
    const float xc = spf + (float)(kk_ % 3) + dx;                              \
    const float yf = floorf(yc), xf = floorf(xc);                              \
    const float wy = yc - yf, wx = xc - xf;                                    \
    const int   yi = (int)yf, xi = (int)xf;     /* padded coords, >= 0 */      \
    const float omy = 1.f - wy, omx = 1.f - wx;                                \
    wgt[P][0] = omy * omx; wgt[P][1] = omy * wx;                               \
    wgt[P][2] = wy * omx;  wgt[P][3] = wy * wx;                                \
    const unsigned short* p0 = xb + (yi * PW + xi) * 256 + g_ * 64;            \
    const unsigned short* p1 = p0 + PW * 256;                                  \
    gA[P][0] = *(const uint4*)(p0);         gA[P][1] = *(const uint4*)(p0+8);  \
    gB[P][0] = *(const uint4*)(p0 + 256);   gB[P][1] = *(const uint4*)(p0+264);\
    gC[P][0] = *(const uint4*)(p1);         gC[P][1] = *(const uint4*)(p1+8);  \
    gD[P][0] = *(const uint4*)(p1 + 256);   gD[P][1] = *(const uint4*)(p1+264);\
} while (0)

#define STAGE_W(t, buf) do {                                                   \
    const unsigned short* src = wb + (size_t)(t) * 16384;                      \
    _Pragma("unroll")                                                          \
    for (int j = 0; j < 8; ++j) {                                              \
        const int off = (j * 256 + ptid) * 8;                                  \
        __builtin_amdgcn_global_load_lds((gptr_t)(src + off),                  \
                                         (lptr_t)(&s_W[buf][0] + off),         \
                                         16, 0, 0);                            \
    }                                                                          \
} while (0)

#define BIL1(Aq, Bq, Cq, Dq, P, res) do {                                      \
    const unsigned int av[4] = {Aq.x, Aq.y, Aq.z, Aq.w};                       \
    const unsigned int bv[4] = {Bq.x, Bq.y, Bq.z, Bq.w};                       \
    const unsigned int cv[4] = {Cq.x, Cq.y, Cq.z, Cq.w};                       \
    const unsigned int dv[4] = {Dq.x, Dq.y, Dq.z, Dq.w};                       \
    _Pragma("unroll")                                                          \
    for (int q = 0; q < 4; ++q) {                                              \
        float rl = wgt[P][0] * f_lo(av[q]);                                    \
        rl = fmaf(wgt[P][1], f_lo(bv[q]), rl);                                 \
        rl = fmaf(wgt[P][2], f_lo(cv[q]), rl);                                 \
        rl = fmaf(wgt[P][3], f_lo(dv[q]), rl);                                 \
        float rh = wgt[P][0] * f_hi(av[q]);                                    \
        rh = fmaf(wgt[P][1], f_hi(bv[q]), rh);                                 \
        rh = fmaf(wgt[P][2], f_hi(cv[q]), rh);                                 \
        rh = fmaf(wgt[P][3], f_hi(dv[q]), rh);                                 \
        res[q] = __builtin_amdgcn_perm(__float_as_uint(rh),                    \
                                       __float_as_uint(rl), 0x07060302u);      \
    }                                                                          \
} while (0)

#define BILIN2(P, SB) do {                                                     \
    unsigned int r0[4], r1[4];                                                 \
    BIL1(gA[P][0], gB[P][0], gC[P][0], gD[P][0], P, r0);                       \
    BIL1(gA[P][1], gB[P][1], gC[P][1], gD[P][1], P, r1);                       \
    *(uint4*)(&s_S[SB][0] + sp * 64 + (((cq + 0) ^ (sp & 7)) * 8)) =           \
        make_uint4(r0[0], r0[1], r0[2], r0[3]);                                \
    *(uint4*)(&s_S[SB][0] + sp * 64 + (((cq + 1) ^ (sp & 7)) * 8)) =           \
        make_uint4(r1[0], r1[1], r1[2], r1[3]);                                \
} while (0)

// Producer tap t. Entering queue (per wave): G(t+1)[8], D(t+1)[8].
// Issue G(t+2)[8] + D(t+2)[8] -> 32. vmcnt(24) retires G(t+1) -> bilinear.
// vmcnt(16) retires D(t+1). G(t+2)+D(t+2) cross the barrier in flight.
#define PTAP(t, GSN, DBUF, GSO, SBUF) do {                                     \
    ISSUE_G((t) + 2, GSN);                                                     \
    __builtin_amdgcn_sched_barrier(0);                                         \
    STAGE_W((t) + 2, DBUF);                                                    \
    __builtin_amdgcn_sched_barrier(0);                                         \
    asm volatile("s_waitcnt vmcnt(24)" ::: "memory");                          \
    __builtin_amdgcn_sched_barrier(0);                                         \
    BILIN2(GSO, SBUF);                                                         \
    __builtin_amdgcn_sched_barrier(0);                                         \
    asm volatile("s_waitcnt vmcnt(16) lgkmcnt(0)" ::: "memory");               \
    BAR();                                                                     \
} while (0)

        // ---- prologue: G(0),D(0),G(1),D(1); S[0]; retire D(0); barrier ----
        ISSUE_G(0, 0);
        __builtin_amdgcn_sched_barrier(0);
        STAGE_W(0, 0);
        __builtin_amdgcn_sched_barrier(0);
        ISSUE_G(1, 1);
        __builtin_amdgcn_sched_barrier(0);
        STAGE_W(1, 1);
        __builtin_amdgcn_sched_barrier(0);
        asm volatile("s_waitcnt vmcnt(24)" ::: "memory");   // G(0) done
        __builtin_amdgcn_sched_barrier(0);
        BILIN2(0, 0);
        __builtin_amdgcn_sched_barrier(0);
        asm volatile("s_waitcnt vmcnt(16) lgkmcnt(0)" ::: "memory"); // D(0) done
        BAR();                                              // barrier #1

        // ---- taps 0..29 (period-6 static buffers), then 30..33, 34, 35 ----
        for (int tb = 0; tb < 30; tb += 6) {
            PTAP(tb + 0, 0, 2, 1, 1);
            PTAP(tb + 1, 1, 0, 0, 0);
            PTAP(tb + 2, 0, 1, 1, 1);
            PTAP(tb + 3, 1, 2, 0, 0);
            PTAP(tb + 4, 0, 0, 1, 1);
            PTAP(tb + 5, 1, 1, 0, 0);
        }
        PTAP(30, 0, 2, 1, 1);
        PTAP(31, 1, 0, 0, 0);
        PTAP(32, 0, 1, 1, 1);
        PTAP(33, 1, 2, 0, 0);
        // tap 34: no issues; retire G(35) -> S[1]; retire D(35); barrier
        asm volatile("s_waitcnt vmcnt(8)" ::: "memory");
        __builtin_amdgcn_sched_barrier(0);
        BILIN2(1, 1);
        __builtin_amdgcn_sched_barrier(0);
        asm volatile("s_waitcnt vmcnt(0) lgkmcnt(0)" ::: "memory");
        BAR();
        // tap 35: producers idle
        BAR();
#undef ISSUE_G
#undef STAGE_W
#undef BIL1
#undef BILIN2
#undef PTAP
    } else {
        // ================= CONSUMERS (waves 0-3) =================
        const int c   = wave;               // outs [c*64, +64)
        const int l15 = lane & 15, kq = lane >> 4, swz = l15 & 7;
        const int p0  = (kq ^ swz) * 8;          // kh=0 chunk pos (shorts)
        const int p1  = ((4 + kq) ^ swz) * 8;    // kh=1 chunk pos

        const unsigned short* wbs[3] = {
            &s_W[0][0] + (c * 64 + l15) * 64,
            &s_W[1][0] + (c * 64 + l15) * 64,
            &s_W[2][0] + (c * 64 + l15) * 64 };
        const unsigned short* sbs[2] = {
            &s_S[0][0] + l15 * 64,
            &s_S[1][0] + l15 * 64 };

        f32x4 acc[16];   // [nt][mt]: 4 px-subtiles x 4 out-subtiles
        #pragma unroll
        for (int i = 0; i < 16; ++i) acc[i] = (f32x4){0.f, 0.f, 0.f, 0.f};

#define CTAP(WB, SB) do {                                                      \
    bf16x8 af0[4], af1[4], bf0[4], bf1[4];                                     \
    _Pragma("unroll")                                                          \
    for (int mt = 0; mt < 4; ++mt) {                                           \
        af0[mt] = *(const bf16x8*)(wbs[WB] + mt * 1024 + p0);                  \
        af1[mt] = *(const bf16x8*)(wbs[WB] + mt * 1024 + p1);                  \
    }                                                                          \
    _Pragma("unroll")                                                          \
    for (int nt = 0; nt < 4; ++nt) {                                           \
        bf0[nt] = *(const bf16x8*)(sbs[SB] + nt * 1024 + p0);                  \
        bf1[nt] = *(const bf16x8*)(sbs[SB] + nt * 1024 + p1);                  \
    }                                                                          \
    __builtin_amdgcn_s_setprio(1);                                             \
    _Pragma("unroll")                                                          \
    for (int nt = 0; nt < 4; ++nt)                                             \
        _Pragma("unroll")                                                      \
        for (int mt = 0; mt < 4; ++mt)                                         \
            acc[nt * 4 + mt] = __builtin_amdgcn_mfma_f32_16x16x32_bf16(        \
                af0[mt], bf0[nt], acc[nt * 4 + mt], 0, 0, 0);                  \
    _Pragma("unroll")                                                          \
    for (int nt = 0; nt < 4; ++nt)                                             \
        _Pragma("unroll")                                                      \
        for (int mt = 0; mt < 4; ++mt)                                         \
            acc[nt * 4 + mt] = __builtin_amdgcn_mfma_f32_16x16x32_bf16(        \
                af1[mt], bf1[nt], acc[nt * 4 + mt], 0, 0, 0);                  \
    __builtin_amdgcn_s_setprio(0);                                             \
} while (0)

        BAR();                              // matches producer prologue barrier
        #pragma unroll 1
        for (int g = 0; g < 6; ++g) {       // taps 6g..6g+5
            CTAP(0, 0); BAR();
            CTAP(1, 1); BAR();
            CTAP(2, 0); BAR();
            CTAP(0, 1); BAR();
            CTAP(1, 0); BAR();
            CTAP(2, 1); BAR();
        }

        // ---- epilogue: fused relu. col=l15 -> px(nt*16+l15), row -> o ----
        #pragma unroll
        for (int nt = 0; nt < 4; ++nt) {
            const int px = nt * 16 + l15;
            #pragma unroll
            for (int mt = 0; mt < 4; ++mt) {
                const int obase = c * 64 + mt * 16 + kq * 4;
                #pragma unroll
                for (int rr = 0; rr < 4; ++rr) {
                    out[(((size_t)b * COUT_ + obase + rr) * H_ + h) * W_ + px] =
                        fmaxf(acc[nt * 4 + mt][rr], 0.f);
                }
            }
        }
#undef CTAP
    }
#undef BAR
}

extern "C" void kernel_launch(void* const* d_in, const int* in_sizes, int n_in,
                              void* d_out, int out_size, void* d_ws, size_t ws_size,
                              hipStream_t stream) {
    const float* x     = (const float*)d_in[0];
    const float* y     = (const float*)d_in[1];
    const float* w_off = (const float*)d_in[2];
    const float* w_def = (const float*)d_in[3];
    float* out = (float*)d_out;

    unsigned short* xTp = (unsigned short*)d_ws;            // 4*80*80*256*2B = 13.1 MB
    unsigned short* wb  = (unsigned short*)d_ws + (size_t)B_ * PH * PW * 256;  // 1.18 MB

    prep_kernel<<<2880, 256, 0, stream>>>(x, xTp, w_def, wb);
    dcn_kernel<<<256, 512, 0, stream>>>(xTp, y, w_off, wb, out);
}